// Round 7
// baseline (34942.453 us; speedup 1.0000x reference)
//
#include <hip/hip_runtime.h>

#define Bb 512
#define Tt 512
#define Ll 256
#define Ff 256
#define Hh 128
#define H3 384
#define NZ 8
#define XC 16
#define OC 8
#define CF 9
#define W3N 1152
#define BBt 2    // batches per CDE block (256 blocks)
#define RT 6     // resident w3 tiles per wave (of 18); rest streamed from L2

__device__ __forceinline__ float sigm(float x){ return 1.0f/(1.0f+expf(-x)); }
__device__ __forceinline__ float softplus_(float x){
  return fmaxf(x, 0.0f) + log1pf(expf(-fabsf(x)));
}
__device__ __forceinline__ float dot4(float4 w, float4 z){
  return w.x*z.x + w.y*z.y + w.z*z.z + w.w*z.w;
}

// ---------------- GRU v2: 768 threads, 2 threads per gate-row ------------------
// Row j handled by threads 2j (half 0: k=0..63) and 2j+1 (half 1: k=64..127);
// halves merge with shfl_xor(1). Weights truly register-resident (64 VGPR).
// mode 0: zx encoder. x = [coeffs_x(16), t]; writes zx (B,T,8)
// mode 1: zy encoder. x = [y_past(8), zx(8), t]; writes final h (B,128)
__global__ __launch_bounds__(768) void gru_kernel(
    const float* __restrict__ xin, const float* __restrict__ zx_in,
    const float* __restrict__ tin,
    const float* __restrict__ wih, const float* __restrict__ whh,
    const float* __restrict__ bias, const float* __restrict__ bn,
    const float* __restrict__ zxlw, const float* __restrict__ zxlb,
    float* __restrict__ out_zx, float* __restrict__ out_h,
    int steps, int mode)
{
  const int b = blockIdx.x;
  const int tid = threadIdx.x;
  const int j = tid >> 1;        // gate row 0..383
  const int half = tid & 1;      // k-half

  float wi[17];
  #pragma unroll
  for (int c = 0; c < 17; c++) wi[c] = wih[j*17 + c];
  const float bj = bias[j];
  float4 wr[16];                 // whh[j][half*64 .. half*64+63]
  {
    const float4* p = reinterpret_cast<const float4*>(whh + (size_t)j*Hh + half*64);
    #pragma unroll
    for (int q = 0; q < 16; q++) wr[q] = p[q];
  }

  __shared__ __align__(16) float s_h[Hh];
  __shared__ float s_i[H3];
  __shared__ float s_g[H3];
  __shared__ float s_x[17];
  __shared__ float s_bn[Hh];
  __shared__ float s_zxlw[NZ*Hh];
  __shared__ float s_red[NZ][17];

  if (tid < Hh){ s_h[tid] = 0.0f; s_bn[tid] = bn[tid]; }
  if (mode == 0){ for (int q = tid; q < NZ*Hh; q += 768) s_zxlw[q] = zxlw[q]; }
  __syncthreads();

  for (int t = 0; t < steps; t++){
    if (mode == 0){
      if (tid < 16) s_x[tid] = xin[(size_t)b*Tt*XC + (size_t)t*XC + tid];
      else if (tid == 16) s_x[16] = tin[t];
    } else {
      if (tid < 8) s_x[tid] = xin[(size_t)b*Ll*NZ + (size_t)t*NZ + tid];
      else if (tid < 16) s_x[tid] = zx_in[(size_t)b*Tt*NZ + (size_t)t*NZ + (tid - 8)];
      else if (tid == 16) s_x[16] = tin[t];
    }
    __syncthreads();
    float ai = bj;
    #pragma unroll
    for (int c = 0; c < 17; c++) ai += wi[c]*s_x[c];
    float g0=0.f, g1=0.f, g2=0.f, g3=0.f;
    {
      const float4* h4p = reinterpret_cast<const float4*>(&s_h[half*64]);
      #pragma unroll
      for (int q = 0; q < 16; q++){
        float4 w = wr[q];
        float4 h4 = h4p[q];
        g0 += w.x*h4.x; g1 += w.y*h4.y; g2 += w.z*h4.z; g3 += w.w*h4.w;
      }
    }
    float g = (g0+g1)+(g2+g3);
    g += __shfl_xor(g, 1, 64);     // merge k-halves (adjacent lanes, same j)
    if (half == 0){ s_i[j] = ai; s_g[j] = g; }
    __syncthreads();
    if (tid < Hh){
      float r  = sigm(s_i[tid]       + s_g[tid]);
      float zz = sigm(s_i[Hh + tid]  + s_g[Hh + tid]);
      float n  = tanhf(s_i[2*Hh+tid] + r*(s_g[2*Hh+tid] + s_bn[tid]));
      s_h[tid] = n + zz*(s_h[tid] - n);
    }
    __syncthreads();
    if (mode == 0){
      if (tid < Hh){
        int o = tid >> 4, m = tid & 15;
        float p = 0.f;
        #pragma unroll
        for (int q = 0; q < 8; q++) p += s_zxlw[o*Hh + m*8 + q]*s_h[m*8 + q];
        s_red[o][m] = p;
      }
      __syncthreads();
      if (tid < NZ){
        float p = zxlb[tid];
        #pragma unroll
        for (int m = 0; m < 16; m++) p += s_red[tid][m];
        out_zx[(size_t)b*Tt*NZ + (size_t)t*NZ + tid] = p;
      }
      __syncthreads();
    }
  }
  if (mode == 1 && tid < Hh) out_h[b*Hh + tid] = s_h[tid];
}

// ---------------- CDE RK4 — FP32, partial register residency + L2 streaming ---
// 256 blocks x 2 batches x 512 threads (8 waves, 2/SIMD -> 256 VGPR cap).
// G1/G2: wave owns cols 16wv..16wv+15; lane (l15=col, g4=k-quarter, 32 regs each).
// G3: wave owns cols 144wv..+143 as 18 tiles of 8 (l7=col, g8=k-eighth, 16 regs);
//     tiles 0..RT-1 register-resident, RT..17 streamed from global (L2-hot).
__global__ __launch_bounds__(512, 2) void cde_fp32_kernel(
    const float* __restrict__ zy_h, const float* __restrict__ zx,
    const float* __restrict__ tin,
    const float* __restrict__ fw1, const float* __restrict__ fb1,
    const float* __restrict__ fw2, const float* __restrict__ fb2,
    const float* __restrict__ fw3, const float* __restrict__ fb3,
    const float* __restrict__ rw,  const float* __restrict__ rb,
    float* __restrict__ yout)
{
  const int tid = threadIdx.x;
  const int wv = tid >> 6, lane = tid & 63;
  const int l15 = lane & 15, g4 = lane >> 4;
  const int l7 = lane & 7,  g8 = lane >> 3;
  const int bg = blockIdx.x * BBt;

  __shared__ __align__(16) float s_zin[BBt][Hh];
  __shared__ __align__(16) float s_h1[BBt][Hh];
  __shared__ __align__(16) float s_h2[BBt][Hh];
  __shared__ float s_o[BBt][W3N];      // raw pre-act, then tanh*dx in place
  __shared__ float s_z[BBt][Hh];
  __shared__ float s_kacc[BBt][Hh];
  __shared__ float s_dx[BBt][CF];
  __shared__ float s_rw[OC*Hh];
  __shared__ float s_rb[OC];
  __shared__ float s_b3[W3N];

  // ---- weights -> registers ----
  const int c12 = 16*wv + l15;
  float4 w1q[8], w2q[8];
  {
    const float4* p1 = reinterpret_cast<const float4*>(fw1 + (size_t)c12*Hh + g4*32);
    const float4* p2 = reinterpret_cast<const float4*>(fw2 + (size_t)c12*Hh + g4*32);
    #pragma unroll
    for (int j = 0; j < 8; j++){ w1q[j] = p1[j]; w2q[j] = p2[j]; }
  }
  const float b1r = fb1[c12], b2r = fb2[c12];
  float4 w3q[RT][4];
  #pragma unroll
  for (int tt = 0; tt < RT; tt++){
    const float4* p3 = reinterpret_cast<const float4*>(
        fw3 + (size_t)(144*wv + 8*tt + l7)*Hh + g8*16);
    #pragma unroll
    for (int j = 0; j < 4; j++) w3q[tt][j] = p3[j];
  }

  for (int idx = tid; idx < W3N; idx += 512) s_b3[idx] = fb3[idx];
  for (int idx = tid; idx < OC*Hh; idx += 512) s_rw[idx] = rw[idx];   // FIXED (was if tid<1024 w/ 512 thr)
  if (tid < OC) s_rb[tid] = rb[tid];
  if (tid < BBt*Hh){
    int b = tid >> 7, h = tid & 127;
    float zv = zy_h[(size_t)(bg + b)*Hh + h];
    s_z[b][h] = zv;
    s_zin[b][h] = zv;
  }
  __syncthreads();

  // y[:, 0, :] via 16-lane shfl-reduced dots (waves 0-3)
  if (tid < 256){
    int b = tid >> 7, r = tid & 127, o = r >> 4, seg = r & 15;
    float p = 0.f;
    #pragma unroll
    for (int q = 0; q < 8; q++)
      p += s_z[b][seg*8 + q]*s_rw[o*Hh + seg*8 + q];
    p += __shfl_xor(p, 1, 64); p += __shfl_xor(p, 2, 64);
    p += __shfl_xor(p, 4, 64); p += __shfl_xor(p, 8, 64);
    if (seg == 0) yout[(size_t)(bg + b)*Ff*OC + o] = s_rb[o] + p;
  }

  for (int i = 0; i < Ff - 1; i++){
    // dX = [diff(zx_future), dt]
    if (tid < BBt*CF){
      int b = tid/CF, c = tid%CF;
      float d;
      if (c < 8){
        const float* zp = zx + (size_t)(bg + b)*Tt*NZ + (size_t)(Ll + i)*NZ + c;
        d = zp[NZ] - zp[0];
      } else {
        d = tin[Ll + i + 1] - tin[Ll + i];
      }
      s_dx[b][c] = d;
    }
    __syncthreads();

    for (int st = 0; st < 4; st++){
      // ---- G1: h1 = softplus(zin @ w1.T + b1) ----
      #pragma unroll
      for (int b = 0; b < BBt; b++){
        const float4* zp = reinterpret_cast<const float4*>(&s_zin[b][g4*32]);
        float p = 0.f;
        #pragma unroll
        for (int j = 0; j < 8; j++) p += dot4(w1q[j], zp[j]);
        p += __shfl_xor(p, 16, 64);
        p += __shfl_xor(p, 32, 64);
        if (lane < 16) s_h1[b][c12] = softplus_(b1r + p);
      }
      __syncthreads();
      // ---- G2: h2 = softplus(h1 @ w2.T + b2) ----
      #pragma unroll
      for (int b = 0; b < BBt; b++){
        const float4* zp = reinterpret_cast<const float4*>(&s_h1[b][g4*32]);
        float p = 0.f;
        #pragma unroll
        for (int j = 0; j < 8; j++) p += dot4(w2q[j], zp[j]);
        p += __shfl_xor(p, 16, 64);
        p += __shfl_xor(p, 32, 64);
        if (lane < 16) s_h2[b][c12] = softplus_(b2r + p);
      }
      __syncthreads();
      // ---- G3 raw: s_o = h2 @ w3.T + b3; resident + streamed tiles ----
      {
        float4 h2q[BBt][4];
        #pragma unroll
        for (int b = 0; b < BBt; b++){
          const float4* hp = reinterpret_cast<const float4*>(&s_h2[b][g8*16]);
          #pragma unroll
          for (int j = 0; j < 4; j++) h2q[b][j] = hp[j];
        }
        const float* w3base = fw3 + (size_t)(144*wv + l7)*Hh + g8*16;
        // resident tiles
        #pragma unroll
        for (int tt = 0; tt < RT; tt++){
          #pragma unroll
          for (int b = 0; b < BBt; b++){
            float p = 0.f;
            #pragma unroll
            for (int j = 0; j < 4; j++) p += dot4(w3q[tt][j], h2q[b][j]);
            p += __shfl_xor(p, 8, 64);
            p += __shfl_xor(p, 16, 64);
            p += __shfl_xor(p, 32, 64);
            if (lane < 8){
              int n = 144*wv + 8*tt + lane;
              s_o[b][n] = s_b3[n] + p;
            }
          }
        }
        // streamed tiles (L2-resident weights), 1-deep prefetch
        float4 cur[4];
        {
          const float4* p3 = reinterpret_cast<const float4*>(w3base + (size_t)(8*RT)*Hh);
          #pragma unroll
          for (int j = 0; j < 4; j++) cur[j] = p3[j];
        }
        for (int tt = RT; tt < 18; tt++){
          const int ttn = (tt < 17) ? tt + 1 : tt;   // clamped (no UB), redundant last load
          float4 nxt[4];
          {
            const float4* p3 = reinterpret_cast<const float4*>(w3base + (size_t)(8*ttn)*Hh);
            #pragma unroll
            for (int j = 0; j < 4; j++) nxt[j] = p3[j];
          }
          #pragma unroll
          for (int b = 0; b < BBt; b++){
            float p = 0.f;
            #pragma unroll
            for (int j = 0; j < 4; j++) p += dot4(cur[j], h2q[b][j]);
            p += __shfl_xor(p, 8, 64);
            p += __shfl_xor(p, 16, 64);
            p += __shfl_xor(p, 32, 64);
            if (lane < 8){
              int n = 144*wv + 8*tt + lane;
              s_o[b][n] = s_b3[n] + p;
            }
          }
          #pragma unroll
          for (int j = 0; j < 4; j++) cur[j] = nxt[j];
        }
      }
      __syncthreads();
      // ---- phase A: o <- tanh(o) * dx[c], spread over all 512 threads ----
      for (int v = tid; v < BBt*W3N; v += 512){
        int b = v / W3N, n = v - b*W3N;
        s_o[b][n] = tanhf(s_o[b][n]) * s_dx[b][n % CF];
      }
      __syncthreads();
      // ---- phase B: k_h = sum_c  +  RK4 combine ----
      if (tid < BBt*Hh){
        int b = tid >> 7, h = tid & 127;
        float kc = 0.f;
        #pragma unroll
        for (int c = 0; c < CF; c++) kc += s_o[b][h*CF + c];
        float zv = s_z[b][h], zin;
        if      (st == 0){ s_kacc[b][h] = kc;        zin = zv + 0.5f*kc; }
        else if (st == 1){ s_kacc[b][h] += 2.f*kc;   zin = zv + 0.5f*kc; }
        else if (st == 2){ s_kacc[b][h] += 2.f*kc;   zin = zv + kc; }
        else { float zn = zv + (s_kacc[b][h] + kc)*(1.f/6.f); s_z[b][h] = zn; zin = zn; }
        s_zin[b][h] = zin;
      }
      __syncthreads();
    }
    // readout y[:, i+1, :]
    if (tid < 256){
      int b = tid >> 7, r = tid & 127, o = r >> 4, seg = r & 15;
      float p = 0.f;
      #pragma unroll
      for (int q = 0; q < 8; q++)
        p += s_z[b][seg*8 + q]*s_rw[o*Hh + seg*8 + q];
      p += __shfl_xor(p, 1, 64); p += __shfl_xor(p, 2, 64);
      p += __shfl_xor(p, 4, 64); p += __shfl_xor(p, 8, 64);
      if (seg == 0) yout[(size_t)(bg + b)*Ff*OC + (size_t)(i + 1)*OC + o] = s_rb[o] + p;
    }
  }
}

extern "C" void kernel_launch(void* const* d_in, const int* in_sizes, int n_in,
                              void* d_out, int out_size, void* d_ws, size_t ws_size,
                              hipStream_t stream)
{
  (void)in_sizes; (void)n_in; (void)out_size; (void)ws_size;
  const float* y_past = (const float*)d_in[0];
  const float* t_in   = (const float*)d_in[1];
  const float* coeffs = (const float*)d_in[2];
  // d_in[3] = input_length (fixed 256)
  const float* zx_wih = (const float*)d_in[4];
  const float* zx_whh = (const float*)d_in[5];
  const float* zx_b   = (const float*)d_in[6];
  const float* zx_bn  = (const float*)d_in[7];
  const float* zxl_w  = (const float*)d_in[8];
  const float* zxl_b  = (const float*)d_in[9];
  const float* zy_wih = (const float*)d_in[10];
  const float* zy_whh = (const float*)d_in[11];
  const float* zy_b   = (const float*)d_in[12];
  const float* zy_bn  = (const float*)d_in[13];
  const float* fw1 = (const float*)d_in[14];
  const float* fb1 = (const float*)d_in[15];
  const float* fw2 = (const float*)d_in[16];
  const float* fb2 = (const float*)d_in[17];
  const float* fw3 = (const float*)d_in[18];
  const float* fb3 = (const float*)d_in[19];
  const float* r_w = (const float*)d_in[20];
  const float* r_b = (const float*)d_in[21];

  float* ws = (float*)d_ws;
  float* zx_buf = ws;                              // B*T*NZ fp32 = 8.39 MB
  float* zy_buf = ws + (size_t)Bb*Tt*NZ;           // B*H fp32   = 256 KB

  gru_kernel<<<Bb, 768, 0, stream>>>(coeffs, nullptr, t_in,
                                     zx_wih, zx_whh, zx_b, zx_bn,
                                     zxl_w, zxl_b, zx_buf, nullptr, Tt, 0);
  gru_kernel<<<Bb, 768, 0, stream>>>(y_past, zx_buf, t_in,
                                     zy_wih, zy_whh, zy_b, zy_bn,
                                     nullptr, nullptr, nullptr, zy_buf, Ll, 1);
  cde_fp32_kernel<<<Bb/BBt, 512, 0, stream>>>(zy_buf, zx_buf, t_in,
                                              fw1, fb1, fw2, fb2, fw3, fb3,
                                              r_w, r_b, (float*)d_out);
}

// Round 8
// 22351.479 us; speedup vs baseline: 1.5633x; 1.5633x over previous
//
#include <hip/hip_runtime.h>

#define Bb 512
#define Tt 512
#define Ll 256
#define Ff 256
#define Hh 128
#define H3 384
#define NZ 8
#define XC 16
#define OC 8
#define CF 9
#define W3N 1152
#define BBt 2    // batches per CDE block (256 blocks = 1/CU)
#define RT 6     // resident w3 tiles per wave (of 18); rest streamed from L2

__device__ __forceinline__ float sigm(float x){ return 1.0f/(1.0f+expf(-x)); }
__device__ __forceinline__ float softplus_(float x){
  return fmaxf(x, 0.0f) + log1pf(expf(-fabsf(x)));
}
__device__ __forceinline__ float dot4(float4 w, float4 z){
  return w.x*z.x + w.y*z.y + w.z*z.z + w.w*z.w;
}

// ---------------- GRU v2: 768 threads, 2 threads per gate-row ------------------
// Row j handled by threads 2j (k=0..63) and 2j+1 (k=64..127); halves merge with
// shfl_xor(1). Weights register-resident (16 float4 = 64 VGPR).
__global__ __launch_bounds__(768) void gru_kernel(
    const float* __restrict__ xin, const float* __restrict__ zx_in,
    const float* __restrict__ tin,
    const float* __restrict__ wih, const float* __restrict__ whh,
    const float* __restrict__ bias, const float* __restrict__ bn,
    const float* __restrict__ zxlw, const float* __restrict__ zxlb,
    float* __restrict__ out_zx, float* __restrict__ out_h,
    int steps, int mode)
{
  const int b = blockIdx.x;
  const int tid = threadIdx.x;
  const int j = tid >> 1;        // gate row 0..383
  const int half = tid & 1;      // k-half

  float wi[17];
  #pragma unroll
  for (int c = 0; c < 17; c++) wi[c] = wih[j*17 + c];
  const float bj = bias[j];
  float4 wr[16];                 // whh[j][half*64 .. half*64+63]
  {
    const float4* p = reinterpret_cast<const float4*>(whh + (size_t)j*Hh + half*64);
    #pragma unroll
    for (int q = 0; q < 16; q++) wr[q] = p[q];
  }

  __shared__ __align__(16) float s_h[Hh];
  __shared__ float s_i[H3];
  __shared__ float s_g[H3];
  __shared__ float s_x[17];
  __shared__ float s_bn[Hh];
  __shared__ float s_zxlw[NZ*Hh];
  __shared__ float s_red[NZ][17];

  if (tid < Hh){ s_h[tid] = 0.0f; s_bn[tid] = bn[tid]; }
  if (mode == 0){ for (int q = tid; q < NZ*Hh; q += 768) s_zxlw[q] = zxlw[q]; }
  __syncthreads();

  for (int t = 0; t < steps; t++){
    if (mode == 0){
      if (tid < 16) s_x[tid] = xin[(size_t)b*Tt*XC + (size_t)t*XC + tid];
      else if (tid == 16) s_x[16] = tin[t];
    } else {
      if (tid < 8) s_x[tid] = xin[(size_t)b*Ll*NZ + (size_t)t*NZ + tid];
      else if (tid < 16) s_x[tid] = zx_in[(size_t)b*Tt*NZ + (size_t)t*NZ + (tid - 8)];
      else if (tid == 16) s_x[16] = tin[t];
    }
    __syncthreads();
    float ai = bj;
    #pragma unroll
    for (int c = 0; c < 17; c++) ai += wi[c]*s_x[c];
    float g0=0.f, g1=0.f, g2=0.f, g3=0.f;
    {
      const float4* h4p = reinterpret_cast<const float4*>(&s_h[half*64]);
      #pragma unroll
      for (int q = 0; q < 16; q++){
        float4 w = wr[q];
        float4 h4 = h4p[q];
        g0 += w.x*h4.x; g1 += w.y*h4.y; g2 += w.z*h4.z; g3 += w.w*h4.w;
      }
    }
    float g = (g0+g1)+(g2+g3);
    g += __shfl_xor(g, 1, 64);     // merge k-halves (adjacent lanes, same j)
    if (half == 0){ s_i[j] = ai; s_g[j] = g; }
    __syncthreads();
    if (tid < Hh){
      float r  = sigm(s_i[tid]       + s_g[tid]);
      float zz = sigm(s_i[Hh + tid]  + s_g[Hh + tid]);
      float n  = tanhf(s_i[2*Hh+tid] + r*(s_g[2*Hh+tid] + s_bn[tid]));
      s_h[tid] = n + zz*(s_h[tid] - n);
    }
    __syncthreads();
    if (mode == 0){
      if (tid < Hh){
        int o = tid >> 4, m = tid & 15;
        float p = 0.f;
        #pragma unroll
        for (int q = 0; q < 8; q++) p += s_zxlw[o*Hh + m*8 + q]*s_h[m*8 + q];
        s_red[o][m] = p;
      }
      __syncthreads();
      if (tid < NZ){
        float p = zxlb[tid];
        #pragma unroll
        for (int m = 0; m < 16; m++) p += s_red[tid][m];
        out_zx[(size_t)b*Tt*NZ + (size_t)t*NZ + tid] = p;
      }
      __syncthreads();
    }
  }
  if (mode == 1 && tid < Hh) out_h[b*Hh + tid] = s_h[tid];
}

// ---------------- CDE RK4 — FP32, true register residency via waves_per_eu -----
// 256 blocks (1/CU) x 2 batches x 512 threads (8 waves = 2/SIMD).
// amdgpu_waves_per_eu(2,2): allocator budget = 512/2 = 256 VGPR -> arrays stay
// in registers (round-7 spill fix). Budget: w1(32)+w2(32)+w3[RT=6](96)+h2(32)
// +prefetch(32)+temps ~ 244.
__global__ __launch_bounds__(512)
__attribute__((amdgpu_waves_per_eu(2, 2)))
void cde_fp32_kernel(
    const float* __restrict__ zy_h, const float* __restrict__ zx,
    const float* __restrict__ tin,
    const float* __restrict__ fw1, const float* __restrict__ fb1,
    const float* __restrict__ fw2, const float* __restrict__ fb2,
    const float* __restrict__ fw3, const float* __restrict__ fb3,
    const float* __restrict__ rw,  const float* __restrict__ rb,
    float* __restrict__ yout)
{
  const int tid = threadIdx.x;
  const int wv = tid >> 6, lane = tid & 63;
  const int l15 = lane & 15, g4 = lane >> 4;
  const int l7 = lane & 7,  g8 = lane >> 3;
  const int bg = blockIdx.x * BBt;

  __shared__ __align__(16) float s_zin[BBt][Hh];
  __shared__ __align__(16) float s_h1[BBt][Hh];
  __shared__ __align__(16) float s_h2[BBt][Hh];
  __shared__ float s_o[BBt][W3N];      // raw pre-act, then tanh*dx in place
  __shared__ float s_z[BBt][Hh];
  __shared__ float s_kacc[BBt][Hh];
  __shared__ float s_dx[BBt][CF];
  __shared__ float s_rw[OC*Hh];
  __shared__ float s_rb[OC];
  __shared__ float s_b3[W3N];

  // ---- weights -> registers ----
  const int c12 = 16*wv + l15;
  float4 w1q[8], w2q[8];
  {
    const float4* p1 = reinterpret_cast<const float4*>(fw1 + (size_t)c12*Hh + g4*32);
    const float4* p2 = reinterpret_cast<const float4*>(fw2 + (size_t)c12*Hh + g4*32);
    #pragma unroll
    for (int j = 0; j < 8; j++){ w1q[j] = p1[j]; w2q[j] = p2[j]; }
  }
  const float b1r = fb1[c12], b2r = fb2[c12];
  float4 w3q[RT][4];
  #pragma unroll
  for (int tt = 0; tt < RT; tt++){
    const float4* p3 = reinterpret_cast<const float4*>(
        fw3 + (size_t)(144*wv + 8*tt + l7)*Hh + g8*16);
    #pragma unroll
    for (int j = 0; j < 4; j++) w3q[tt][j] = p3[j];
  }

  for (int idx = tid; idx < W3N; idx += 512) s_b3[idx] = fb3[idx];
  for (int idx = tid; idx < OC*Hh; idx += 512) s_rw[idx] = rw[idx];
  if (tid < OC) s_rb[tid] = rb[tid];
  if (tid < BBt*Hh){
    int b = tid >> 7, h = tid & 127;
    float zv = zy_h[(size_t)(bg + b)*Hh + h];
    s_z[b][h] = zv;
    s_zin[b][h] = zv;
  }
  __syncthreads();

  // y[:, 0, :] via 16-lane shfl-reduced dots (waves 0-3)
  if (tid < 256){
    int b = tid >> 7, r = tid & 127, o = r >> 4, seg = r & 15;
    float p = 0.f;
    #pragma unroll
    for (int q = 0; q < 8; q++)
      p += s_z[b][seg*8 + q]*s_rw[o*Hh + seg*8 + q];
    p += __shfl_xor(p, 1, 64); p += __shfl_xor(p, 2, 64);
    p += __shfl_xor(p, 4, 64); p += __shfl_xor(p, 8, 64);
    if (seg == 0) yout[(size_t)(bg + b)*Ff*OC + o] = s_rb[o] + p;
  }

  for (int i = 0; i < Ff - 1; i++){
    // dX = [diff(zx_future), dt]
    if (tid < BBt*CF){
      int b = tid/CF, c = tid%CF;
      float d;
      if (c < 8){
        const float* zp = zx + (size_t)(bg + b)*Tt*NZ + (size_t)(Ll + i)*NZ + c;
        d = zp[NZ] - zp[0];
      } else {
        d = tin[Ll + i + 1] - tin[Ll + i];
      }
      s_dx[b][c] = d;
    }
    __syncthreads();

    for (int st = 0; st < 4; st++){
      // ---- G1: h1 = softplus(zin @ w1.T + b1) ----
      #pragma unroll
      for (int b = 0; b < BBt; b++){
        const float4* zp = reinterpret_cast<const float4*>(&s_zin[b][g4*32]);
        float p = 0.f;
        #pragma unroll
        for (int j = 0; j < 8; j++) p += dot4(w1q[j], zp[j]);
        p += __shfl_xor(p, 16, 64);
        p += __shfl_xor(p, 32, 64);
        if (lane < 16) s_h1[b][c12] = softplus_(b1r + p);
      }
      __syncthreads();
      // ---- G2: h2 = softplus(h1 @ w2.T + b2) ----
      #pragma unroll
      for (int b = 0; b < BBt; b++){
        const float4* zp = reinterpret_cast<const float4*>(&s_h1[b][g4*32]);
        float p = 0.f;
        #pragma unroll
        for (int j = 0; j < 8; j++) p += dot4(w2q[j], zp[j]);
        p += __shfl_xor(p, 16, 64);
        p += __shfl_xor(p, 32, 64);
        if (lane < 16) s_h2[b][c12] = softplus_(b2r + p);
      }
      __syncthreads();
      // ---- G3 raw: s_o = h2 @ w3.T + b3; resident + streamed tiles ----
      {
        // h2 k-eighth cache, named (guaranteed SROA)
        float4 h2a0, h2a1, h2a2, h2a3, h2b0, h2b1, h2b2, h2b3;
        {
          const float4* hp0 = reinterpret_cast<const float4*>(&s_h2[0][g8*16]);
          const float4* hp1 = reinterpret_cast<const float4*>(&s_h2[1][g8*16]);
          h2a0 = hp0[0]; h2a1 = hp0[1]; h2a2 = hp0[2]; h2a3 = hp0[3];
          h2b0 = hp1[0]; h2b1 = hp1[1]; h2b2 = hp1[2]; h2b3 = hp1[3];
        }
        const float* w3base = fw3 + (size_t)(144*wv + l7)*Hh + g8*16;
        // resident tiles
        #pragma unroll
        for (int tt = 0; tt < RT; tt++){
          float p0 = dot4(w3q[tt][0], h2a0) + dot4(w3q[tt][1], h2a1)
                   + dot4(w3q[tt][2], h2a2) + dot4(w3q[tt][3], h2a3);
          float p1 = dot4(w3q[tt][0], h2b0) + dot4(w3q[tt][1], h2b1)
                   + dot4(w3q[tt][2], h2b2) + dot4(w3q[tt][3], h2b3);
          p0 += __shfl_xor(p0, 8, 64); p0 += __shfl_xor(p0, 16, 64); p0 += __shfl_xor(p0, 32, 64);
          p1 += __shfl_xor(p1, 8, 64); p1 += __shfl_xor(p1, 16, 64); p1 += __shfl_xor(p1, 32, 64);
          if (lane < 8){
            int n = 144*wv + 8*tt + lane;
            s_o[0][n] = s_b3[n] + p0;
            s_o[1][n] = s_b3[n] + p1;
          }
        }
        // streamed tiles (L2-resident weights), 2-deep pipeline, named regs
        float4 c0, c1, c2, c3, n0, n1, n2, n3;
        {
          const float4* pA = reinterpret_cast<const float4*>(w3base + (size_t)(8*RT)*Hh);
          const float4* pB = reinterpret_cast<const float4*>(w3base + (size_t)(8*(RT+1))*Hh);
          c0 = pA[0]; c1 = pA[1]; c2 = pA[2]; c3 = pA[3];
          n0 = pB[0]; n1 = pB[1]; n2 = pB[2]; n3 = pB[3];
        }
        for (int tt = RT; tt < 18; tt++){
          const int ttn = (tt + 2 < 18) ? tt + 2 : tt;   // clamped redundant tail load
          float4 f0, f1, f2, f3;
          {
            const float4* pF = reinterpret_cast<const float4*>(w3base + (size_t)(8*ttn)*Hh);
            f0 = pF[0]; f1 = pF[1]; f2 = pF[2]; f3 = pF[3];
          }
          float p0 = dot4(c0, h2a0) + dot4(c1, h2a1) + dot4(c2, h2a2) + dot4(c3, h2a3);
          float p1 = dot4(c0, h2b0) + dot4(c1, h2b1) + dot4(c2, h2b2) + dot4(c3, h2b3);
          p0 += __shfl_xor(p0, 8, 64); p0 += __shfl_xor(p0, 16, 64); p0 += __shfl_xor(p0, 32, 64);
          p1 += __shfl_xor(p1, 8, 64); p1 += __shfl_xor(p1, 16, 64); p1 += __shfl_xor(p1, 32, 64);
          if (lane < 8){
            int n = 144*wv + 8*tt + lane;
            s_o[0][n] = s_b3[n] + p0;
            s_o[1][n] = s_b3[n] + p1;
          }
          c0 = n0; c1 = n1; c2 = n2; c3 = n3;
          n0 = f0; n1 = f1; n2 = f2; n3 = f3;
        }
      }
      __syncthreads();
      // ---- phase A: o <- tanh(o) * dx[c], spread over all 512 threads ----
      for (int v = tid; v < BBt*W3N; v += 512){
        int b = v / W3N, n = v - b*W3N;
        s_o[b][n] = tanhf(s_o[b][n]) * s_dx[b][n % CF];
      }
      __syncthreads();
      // ---- phase B: k_h = sum_c  +  RK4 combine ----
      if (tid < BBt*Hh){
        int b = tid >> 7, h = tid & 127;
        float kc = 0.f;
        #pragma unroll
        for (int c = 0; c < CF; c++) kc += s_o[b][h*CF + c];
        float zv = s_z[b][h], zin;
        if      (st == 0){ s_kacc[b][h] = kc;        zin = zv + 0.5f*kc; }
        else if (st == 1){ s_kacc[b][h] += 2.f*kc;   zin = zv + 0.5f*kc; }
        else if (st == 2){ s_kacc[b][h] += 2.f*kc;   zin = zv + kc; }
        else { float zn = zv + (s_kacc[b][h] + kc)*(1.f/6.f); s_z[b][h] = zn; zin = zn; }
        s_zin[b][h] = zin;
      }
      __syncthreads();
    }
    // readout y[:, i+1, :]
    if (tid < 256){
      int b = tid >> 7, r = tid & 127, o = r >> 4, seg = r & 15;
      float p = 0.f;
      #pragma unroll
      for (int q = 0; q < 8; q++)
        p += s_z[b][seg*8 + q]*s_rw[o*Hh + seg*8 + q];
      p += __shfl_xor(p, 1, 64); p += __shfl_xor(p, 2, 64);
      p += __shfl_xor(p, 4, 64); p += __shfl_xor(p, 8, 64);
      if (seg == 0) yout[(size_t)(bg + b)*Ff*OC + (size_t)(i + 1)*OC + o] = s_rb[o] + p;
    }
  }
}

extern "C" void kernel_launch(void* const* d_in, const int* in_sizes, int n_in,
                              void* d_out, int out_size, void* d_ws, size_t ws_size,
                              hipStream_t stream)
{
  (void)in_sizes; (void)n_in; (void)out_size; (void)ws_size;
  const float* y_past = (const float*)d_in[0];
  const float* t_in   = (const float*)d_in[1];
  const float* coeffs = (const float*)d_in[2];
  // d_in[3] = input_length (fixed 256)
  const float* zx_wih = (const float*)d_in[4];
  const float* zx_whh = (const float*)d_in[5];
  const float* zx_b   = (const float*)d_in[6];
  const float* zx_bn  = (const float*)d_in[7];
  const float* zxl_w  = (const float*)d_in[8];
  const float* zxl_b  = (const float*)d_in[9];
  const float* zy_wih = (const float*)d_in[10];
  const float* zy_whh = (const float*)d_in[11];
  const float* zy_b   = (const float*)d_in[12];
  const float* zy_bn  = (const float*)d_in[13];
  const float* fw1 = (const float*)d_in[14];
  const float* fb1 = (const float*)d_in[15];
  const float* fw2 = (const float*)d_in[16];
  const float* fb2 = (const float*)d_in[17];
  const float* fw3 = (const float*)d_in[18];
  const float* fb3 = (const float*)d_in[19];
  const float* r_w = (const float*)d_in[20];
  const float* r_b = (const float*)d_in[21];

  float* ws = (float*)d_ws;
  float* zx_buf = ws;                              // B*T*NZ fp32 = 8.39 MB
  float* zy_buf = ws + (size_t)Bb*Tt*NZ;           // B*H fp32   = 256 KB

  gru_kernel<<<Bb, 768, 0, stream>>>(coeffs, nullptr, t_in,
                                     zx_wih, zx_whh, zx_b, zx_bn,
                                     zxl_w, zxl_b, zx_buf, nullptr, Tt, 0);
  gru_kernel<<<Bb, 768, 0, stream>>>(y_past, zx_buf, t_in,
                                     zy_wih, zy_whh, zy_b, zy_bn,
                                     nullptr, nullptr, nullptr, zy_buf, Ll, 1);
  cde_fp32_kernel<<<Bb/BBt, 512, 0, stream>>>(zy_buf, zx_buf, t_in,
                                              fw1, fb1, fw2, fb2, fw3, fb3,
                                              r_w, r_b, (float*)d_out);
}